// Round 2
// baseline (675.740 us; speedup 1.0000x reference)
//
#include <hip/hip_runtime.h>
#include <stdint.h>

#define GW 8192
#define GMASK 8191
#define PLANE 67108864   // elements per links plane (8192*8192)

// ---------------- Kernel 1: zero-fill the output mask (256 MB, int32) --------
__global__ void fill_zero_kernel(int4* __restrict__ out, int n4) {
    int i = blockIdx.x * blockDim.x + threadIdx.x;
    if (i < n4) out[i] = make_int4(0, 0, 0, 0);
}

// ---------------- Kernel 2: detect on-device encoding of the bool 'links' ----
// mode 0: 1-byte bool (raw numpy bool_)
// mode 1: int32 0/1
// mode 2: float32 0.0/1.0
__global__ void detect_fmt_kernel(const unsigned char* __restrict__ links, int* __restrict__ flag) {
    __shared__ int c12, c3;
    if (threadIdx.x == 0) { c12 = 0; c3 = 0; }
    __syncthreads();
    int l12 = 0, l3 = 0;
    for (int i = threadIdx.x; i < 16384; i += blockDim.x) {
        unsigned char b = links[i];
        if (b) {
            int m = i & 3;
            if (m == 1 || m == 2) l12++;
            else if (m == 3) l3++;
        }
    }
    atomicAdd(&c12, l12);
    atomicAdd(&c3, l3);
    __syncthreads();
    if (threadIdx.x == 0) {
        // ~45% of sampled bytes are nonzero for raw bool at p=0.45; int32/float32
        // encodings of 0/1 leave bytes at pos%4 in {1,2} all-zero.
        *flag = (c12 > 0) ? 0 : ((c3 > 0) ? 2 : 1);
    }
}

// ---------------- Kernel 3: single-block level-synchronous BFS ----------------
// Visited marker IS the output: out 0 -> unvisited, 1 (int32) -> in cluster.
__global__ void __launch_bounds__(1024)
bfs_kernel(const unsigned char* __restrict__ links8,
           const int* __restrict__ seed_idx,
           unsigned int* __restrict__ out,      // int32 0/1
           int* __restrict__ q, int qcap,
           const int* __restrict__ flag) {
    __shared__ int s_head, s_cur, s_tail, s_mode;
    const int tid = threadIdx.x;

    if (tid == 0) {
        s_mode = *flag;
        int r = seed_idx[0] & GMASK;
        int c = seed_idx[1] & GMASK;
        int s = r * GW + c;
        atomicExch(&out[s], 1u);
        q[0] = s;
        s_head = 0;
        s_tail = 1;
        s_cur  = 1;
    }
    __syncthreads();
    const int mode = s_mode;
    const int32_t* links32 = (const int32_t*)links8;
    const float*   linksf  = (const float*)links8;

    while (true) {
        // s_head/s_cur written only by tid0 between the two barriers below,
        // read by everyone right after a barrier -> uniform break decision.
        int head = s_head;
        int tail = s_cur;
        if (head >= tail) break;

        for (int i = head + tid; i < tail; i += (int)blockDim.x) {
            int s = q[i];
            int r = s >> 13;
            int c = s & GMASK;
            int rp = (r + 1) & GMASK, rm = (r - 1) & GMASK;
            int cp = (c + 1) & GMASK, cm = (c - 1) & GMASK;

            int bidx[4], nbr[4];
            // bond links[0][r][c]   connects (r,c) <-> (r+1,c)
            // bond links[0][r-1][c] connects (r-1,c) <-> (r,c)
            // bond links[1][r][c]   connects (r,c) <-> (r,c+1)
            // bond links[1][r][c-1] connects (r,c-1) <-> (r,c)
            bidx[0] = s;                    nbr[0] = rp * GW + c;
            bidx[1] = rm * GW + c;          nbr[1] = rm * GW + c;
            bidx[2] = PLANE + s;            nbr[2] = r * GW + cp;
            bidx[3] = PLANE + r * GW + cm;  nbr[3] = r * GW + cm;

            #pragma unroll
            for (int k = 0; k < 4; k++) {
                bool open;
                if (mode == 0)      open = links8[bidx[k]] != 0;
                else if (mode == 1) open = links32[bidx[k]] != 0;
                else                open = linksf[bidx[k]] != 0.f;
                if (open) {
                    unsigned int old = atomicExch(&out[nbr[k]], 1u);
                    if (old == 0u) {
                        int pos = atomicAdd(&s_tail, 1);
                        if (pos < qcap) q[pos] = nbr[k];
                    }
                }
            }
        }
        __syncthreads();
        if (tid == 0) { s_head = tail; s_cur = s_tail; }
        __syncthreads();
    }
}

extern "C" void kernel_launch(void* const* d_in, const int* in_sizes, int n_in,
                              void* d_out, int out_size, void* d_ws, size_t ws_size,
                              hipStream_t stream) {
    const unsigned char* links = (const unsigned char*)d_in[0];
    const int* seed = (const int*)d_in[1];

    int* flag = (int*)d_ws;
    int* q    = (int*)((char*)d_ws + 256);
    int  qcap = (int)((ws_size - 256) / sizeof(int));

    int n4 = out_size / 4;  // 16M int4
    fill_zero_kernel<<<(n4 + 255) / 256, 256, 0, stream>>>((int4*)d_out, n4);
    detect_fmt_kernel<<<1, 256, 0, stream>>>(links, flag);
    bfs_kernel<<<1, 1024, 0, stream>>>(links, seed, (unsigned int*)d_out, q, qcap, flag);
}